// Round 1
// baseline (339.385 us; speedup 1.0000x reference)
//
#include <hip/hip_runtime.h>
#include <stdint.h>

// Segment layout (elements in each battle row of 10451 floats):
//  player 9 @0 | status 86 @9 | pinfo 8 @95 | 13 x card(740) @103 | potions 43 @9723
//  | relics 180 @9766 | 5 x monster(101) @9946
// Output row (542 floats): player4 @0 | status16 @4 | pinfo2 @20 | cards 13*32 @22
//  | potions8 @438 | relics16 @446 | monsters 5*16 @462

typedef __attribute__((ext_vector_type(8))) short short8;
typedef __attribute__((ext_vector_type(4))) float f32x4;

__device__ inline unsigned short f2bf(float f) {
  union { float f; uint32_t u; } v; v.f = f;
  uint32_t r = v.u + 0x7FFFu + ((v.u >> 16) & 1u);   // round-to-nearest-even
  return (unsigned short)(r >> 16);
}

__device__ inline void gload_dw(const float* g, float* lds) {
  __builtin_amdgcn_global_load_lds(
      (const __attribute__((address_space(1))) void*)g,
      (__attribute__((address_space(3))) void*)lds, 4, 0, 0);
}

// Unified segment-GEMM: each block computes a 128-row x NOUT tile of one segment.
// A rows are battle sub-segments (4B-aligned only), W is [NOUT][K] row-major fp32.
__global__ __launch_bounds__(256, 4) void seg_gemm(
    const float* __restrict__ battle,
    const float* __restrict__ Wplayer, const float* __restrict__ Wstatus,
    const float* __restrict__ Wpinfo,  const float* __restrict__ Wcard,
    const float* __restrict__ Wpotions,const float* __restrict__ Wrelics,
    const float* __restrict__ Wmonster,
    float* __restrict__ out, const float* __restrict__ zpage)
{
  const int bid = blockIdx.x;
  int bloc, nsub, K, NOUT, soff, ooff;
  const float* wp;
  // cards first (longest running blocks), small segments tail the grid
  if (bid < 3328)      { bloc = bid;        nsub = 13; K = 740; NOUT = 32; soff = 103;  ooff = 22;  wp = Wcard; }
  else if (bid < 4608) { bloc = bid - 3328; nsub = 5;  K = 101; NOUT = 16; soff = 9946; ooff = 462; wp = Wmonster; }
  else if (bid < 4864) { bloc = bid - 4608; nsub = 1;  K = 180; NOUT = 16; soff = 9766; ooff = 446; wp = Wrelics; }
  else if (bid < 5120) { bloc = bid - 4864; nsub = 1;  K = 86;  NOUT = 16; soff = 9;    ooff = 4;   wp = Wstatus; }
  else if (bid < 5376) { bloc = bid - 5120; nsub = 1;  K = 43;  NOUT = 8;  soff = 9723; ooff = 438; wp = Wpotions; }
  else if (bid < 5632) { bloc = bid - 5376; nsub = 1;  K = 9;   NOUT = 4;  soff = 0;    ooff = 0;   wp = Wplayer; }
  else                 { bloc = bid - 5632; nsub = 1;  K = 8;   NOUT = 2;  soff = 95;   ooff = 20;  wp = Wpinfo; }

  const int t    = threadIdx.x;
  const int lane = t & 63;
  const int wv   = t >> 6;          // wave id 0..3, owns rows [wv*32, wv*32+32)
  const int rl   = lane & 15;
  const int kg   = lane >> 4;       // k-group 0..3 (8 k's each)

  __shared__ float lds_a[128 * 32]; // [row][32 k] fp32, 16B-granule XOR-swizzled
  __shared__ float lds_w[32 * 32];  // [col][32 k] fp32, same swizzle

  const int mb = bloc * 128;
  const int r0 = t >> 5;            // 0..7 : this thread's (row%8) in staging

  // Precompute global element offsets of the 16 A-rows this thread stages.
  uint32_t rb[16];
  #pragma unroll
  for (int i = 0; i < 16; ++i) {
    uint32_t m   = (uint32_t)(mb + r0 + 8 * i);
    uint32_t b   = m / (uint32_t)nsub;
    uint32_t sub = m - b * (uint32_t)nsub;
    rb[i] = b * 10451u + (uint32_t)soff + sub * (uint32_t)K;
  }

  // Staging source pre-swizzle: LDS is written linearly (slot = row*32 + klin);
  // source element k is granule-XOR'd so that fragment reads are conflict-free.
  const int klin = t & 31;
  const int lk   = (((klin >> 2) ^ r0) << 2) | (klin & 3);  // logical k, 0..31

  f32x4 acc[2][2] = {};
  const int nfc = (NOUT > 16) ? 2 : 1;
  const int nch = (K + 31) >> 5;

  for (int ch = 0; ch < nch; ++ch) {
    const int k0 = ch << 5;
    const int kk = k0 + lk;
    // ---- stage A tile: 128 rows x 32 k, fp32, via global_load_lds dword ----
    #pragma unroll
    for (int i = 0; i < 16; ++i) {
      const float* sp = (kk < K) ? (battle + rb[i] + kk) : zpage;
      gload_dw(sp, &lds_a[i * 256 + t]);
    }
    // ---- stage W tile: 32 cols x 32 k (zero-padded beyond NOUT / K) ----
    #pragma unroll
    for (int i = 0; i < 4; ++i) {
      const int col = r0 + 8 * i;
      const float* sp = (col < NOUT && kk < K) ? (wp + col * K + kk) : zpage;
      gload_dw(sp, &lds_w[i * 256 + t]);
    }
    __syncthreads();   // drains vmcnt -> DMA'd LDS visible to all waves

    // ---- fragments: read swizzled fp32, convert to bf16 in registers ----
    short8 af[2], bfr[2];
    #pragma unroll
    for (int mf = 0; mf < 2; ++mf) {
      const int r  = wv * 32 + mf * 16 + rl;
      const int g0 = (2 * kg) ^ (r & 7);
      const int g1 = (2 * kg + 1) ^ (r & 7);
      f32x4 lo = *(const f32x4*)&lds_a[r * 32 + g0 * 4];
      f32x4 hi = *(const f32x4*)&lds_a[r * 32 + g1 * 4];
      af[mf][0] = (short)f2bf(lo[0]); af[mf][1] = (short)f2bf(lo[1]);
      af[mf][2] = (short)f2bf(lo[2]); af[mf][3] = (short)f2bf(lo[3]);
      af[mf][4] = (short)f2bf(hi[0]); af[mf][5] = (short)f2bf(hi[1]);
      af[mf][6] = (short)f2bf(hi[2]); af[mf][7] = (short)f2bf(hi[3]);
    }
    #pragma unroll
    for (int nf = 0; nf < 2; ++nf) {
      if (nf < nfc) {
        const int c  = nf * 16 + rl;
        const int g0 = (2 * kg) ^ (c & 7);
        const int g1 = (2 * kg + 1) ^ (c & 7);
        f32x4 lo = *(const f32x4*)&lds_w[c * 32 + g0 * 4];
        f32x4 hi = *(const f32x4*)&lds_w[c * 32 + g1 * 4];
        bfr[nf][0] = (short)f2bf(lo[0]); bfr[nf][1] = (short)f2bf(lo[1]);
        bfr[nf][2] = (short)f2bf(lo[2]); bfr[nf][3] = (short)f2bf(lo[3]);
        bfr[nf][4] = (short)f2bf(hi[0]); bfr[nf][5] = (short)f2bf(hi[1]);
        bfr[nf][6] = (short)f2bf(hi[2]); bfr[nf][7] = (short)f2bf(hi[3]);
      }
    }
    #pragma unroll
    for (int mf = 0; mf < 2; ++mf)
      #pragma unroll
      for (int nf = 0; nf < 2; ++nf)
        if (nf < nfc)
          acc[mf][nf] = __builtin_amdgcn_mfma_f32_16x16x32_bf16(af[mf], bfr[nf], acc[mf][nf], 0, 0, 0);
    __syncthreads();   // protect LDS from next chunk's staging
  }

  // ---- epilogue: C/D layout col = lane&15, row = (lane>>4)*4 + q ----
  #pragma unroll
  for (int mf = 0; mf < 2; ++mf) {
    #pragma unroll
    for (int q = 0; q < 4; ++q) {
      uint32_t m   = (uint32_t)(mb + wv * 32 + mf * 16 + (lane >> 4) * 4 + q);
      uint32_t b   = m / (uint32_t)nsub;
      uint32_t sub = m - b * (uint32_t)nsub;
      uint32_t ob  = b * 542u + (uint32_t)ooff + sub * (uint32_t)NOUT;
      #pragma unroll
      for (int nf = 0; nf < 2; ++nf) {
        if (nf < nfc) {
          const int col = nf * 16 + rl;
          if (col < NOUT) out[ob + col] = acc[mf][nf][q];
        }
      }
    }
  }
}

extern "C" void kernel_launch(void* const* d_in, const int* in_sizes, int n_in,
                              void* d_out, int out_size, void* d_ws, size_t ws_size,
                              hipStream_t stream) {
  const float* battle   = (const float*)d_in[0];
  const float* Wplayer  = (const float*)d_in[1];
  const float* Wstatus  = (const float*)d_in[2];
  const float* Wpinfo   = (const float*)d_in[3];
  const float* Wcard    = (const float*)d_in[4];
  const float* Wpotions = (const float*)d_in[5];
  const float* Wrelics  = (const float*)d_in[6];
  const float* Wmonster = (const float*)d_in[7];
  float* out = (float*)d_out;
  const float* zpage = (const float*)d_ws;

  // zero page for padded staging lanes (graph-capture-safe async memset)
  hipMemsetAsync(d_ws, 0, 256, stream);

  dim3 grid(5888), block(256);
  hipLaunchKernelGGL(seg_gemm, grid, block, 0, stream,
                     battle, Wplayer, Wstatus, Wpinfo, Wcard, Wpotions,
                     Wrelics, Wmonster, out, zpage);
}